// Round 2
// baseline (448.230 us; speedup 1.0000x reference)
//
#include <hip/hip_runtime.h>
#include <math.h>

#define IN_FEATS 64
#define N_NODES 100000
#define N_EDGES 1600000

// ---------------------------------------------------------------------------
// Kernel 1: per-(edge,feature) message computation + scatter-add into agg.
// agg lives in d_out ([N_NODES, 64] f32) which we zero first.
// ---------------------------------------------------------------------------
__global__ __launch_bounds__(256) void schnet_edge_kernel(
    const float* __restrict__ h,
    const float* __restrict__ dist,
    const int* __restrict__ src_idx,
    const int* __restrict__ dst_idx,
    float* __restrict__ agg)
{
    long long idx = (long long)blockIdx.x * 256 + threadIdx.x;
    int e = (int)(idx >> 6);
    if (e >= N_EDGES) return;
    int k = (int)(idx & 63);

    float d = dist[e];                       // broadcast within the 64-lane row
    float mu = (float)k * (1.0f / 63.0f);    // linspace(0, 1, 64)
    float t = d - mu;
    float rbf = __expf(-64.0f * t * t);      // gamma = 64/(1-0)

    // smooth cutoff: 1 below 0.8, 0 above 1.0, cosine ramp between
    float x  = (d - 0.8f) * 5.0f;            // /(1.0-0.8)
    float xc = fminf(fmaxf(x, 0.0f), 1.0f);
    float ramp = 0.5f * (__cosf(3.14159265358979323846f * xc) + 1.0f);
    float fc = (d <= 0.8f) ? 1.0f : ((d >= 1.0f) ? 0.0f : ramp);

    int s  = src_idx[e];
    int dn = dst_idx[e];
    float val = h[(long long)s * 64 + k] * rbf * fc;
    atomicAdd(&agg[(long long)dn * 64 + k], val);
}

// ---------------------------------------------------------------------------
// Kernel 2: per-node MLP, in place on d_out.
// out[n] = softplus(agg[n] @ W1 + b1) @ W2 + b2
// 4 nodes per 256-thread block, 64 lanes per node; W1/W2 staged in LDS.
// ---------------------------------------------------------------------------
__global__ __launch_bounds__(256) void schnet_mlp_kernel(
    float* __restrict__ io,
    const float* __restrict__ W1, const float* __restrict__ b1,
    const float* __restrict__ W2, const float* __restrict__ b2)
{
    __shared__ float sW1[64 * 64];
    __shared__ float sW2[64 * 64];
    __shared__ float sRow[4][64];
    __shared__ float sHid[4][64];

    int tid = threadIdx.x;
    for (int i = tid; i < 64 * 64; i += 256) {
        sW1[i] = W1[i];
        sW2[i] = W2[i];
    }
    __syncthreads();

    int lane = tid & 63;
    int g    = tid >> 6;
    float bb1 = b1[lane];
    float bb2 = b2[lane];

    for (int base = blockIdx.x * 4; base < N_NODES; base += gridDim.x * 4) {
        int node = base + g;
        if (node < N_NODES) sRow[g][lane] = io[(long long)node * 64 + lane];
        __syncthreads();

        float acc = bb1;
        #pragma unroll
        for (int k = 0; k < 64; ++k)
            acc = fmaf(sRow[g][k], sW1[k * 64 + lane], acc);

        // softplus = log1p(exp(x)), stable
        float hid = (acc > 20.0f) ? acc : log1pf(__expf(acc));
        sHid[g][lane] = hid;
        __syncthreads();

        float acc2 = bb2;
        #pragma unroll
        for (int k = 0; k < 64; ++k)
            acc2 = fmaf(sHid[g][k], sW2[k * 64 + lane], acc2);

        if (node < N_NODES) io[(long long)node * 64 + lane] = acc2;
        __syncthreads();
    }
}

extern "C" void kernel_launch(void* const* d_in, const int* in_sizes, int n_in,
                              void* d_out, int out_size, void* d_ws, size_t ws_size,
                              hipStream_t stream) {
    const float* h    = (const float*)d_in[0];
    const float* dist = (const float*)d_in[1];
    const float* W1   = (const float*)d_in[2];
    const float* b1   = (const float*)d_in[3];
    const float* W2   = (const float*)d_in[4];
    const float* b2   = (const float*)d_in[5];
    const int* src    = (const int*)d_in[6];
    const int* dst    = (const int*)d_in[7];
    float* out        = (float*)d_out;

    // zero the aggregation buffer (= d_out) each call
    hipMemsetAsync(out, 0, (size_t)N_NODES * IN_FEATS * sizeof(float), stream);

    // edge scatter
    long long total = (long long)N_EDGES * 64;
    int eblocks = (int)((total + 255) / 256);
    schnet_edge_kernel<<<eblocks, 256, 0, stream>>>(h, dist, src, dst, out);

    // node MLP (in place)
    schnet_mlp_kernel<<<2048, 256, 0, stream>>>(out, W1, b1, W2, b2);
}